// Round 11
// baseline (193.638 us; speedup 1.0000x reference)
//
#include <hip/hip_runtime.h>
#include <cmath>

#define N_TOK 8192
#define DIM   384
#define NEXP  8
#define HID   1536
#define OUTD  384
#define CAP_MT 72        // 32-row gather tiles per expert (2304 tokens, mean 2048 + 6 sigma)
#define CAP_TOK 2304
#define CAP_TB 18        // 128-row blocks per expert (gemm1)
#define CAP_TB2 36       // 64-row blocks per expert (gemm2)

typedef __attribute__((ext_vector_type(8)))  __bf16 bf16x8;
typedef __attribute__((ext_vector_type(16))) float  f32x16;
typedef __attribute__((ext_vector_type(4)))  float  f32x4;          // nontemporal builtins
typedef __attribute__((ext_vector_type(8)))  unsigned short u16x8;  // nontemporal bf16 loads

__device__ __forceinline__ unsigned short f2bf(float f) {
    unsigned u = __float_as_uint(f);
    u += 0x7FFF + ((u >> 16) & 1);          // round-to-nearest-even
    return (unsigned short)(u >> 16);
}

__device__ __forceinline__ float bf2f(unsigned short s) {
    return __uint_as_float(((unsigned)s) << 16);
}

// gelu via A&S 7.1.26 with v_rcp_f32 (1 ulp) instead of IEEE div.
// R7 lesson: the regression there was the ~10-op IEEE div expansion, not the
// polynomial; rcpf + __expf gives ~14 VALU ops vs ~25-30 for libm erff.
// erf err <= 1.5e-7 + ~1e-7 rcp -> far below bf16 h quantum.
__device__ __forceinline__ float gelu_fast(float x) {
    float a  = 0.70710678118654752f * x;
    float ax = fabsf(a);
    float t  = __builtin_amdgcn_rcpf(fmaf(0.3275911f, ax, 1.0f));
    float y  = t * (0.254829592f + t * (-0.284496736f + t * (1.421413741f
             + t * (-1.453152027f + t * 1.061405429f))));
    float er = 1.0f - y * __expf(-ax * ax);
    er = copysignf(er, a);
    return 0.5f * x * (1.0f + er);
}

// async global->LDS, 16B per lane; LDS dest = wave-uniform tile base (HW adds lane*16)
__device__ __forceinline__ void cp16(const unsigned short* g, unsigned short* l) {
    __builtin_amdgcn_global_load_lds(
        (const __attribute__((address_space(1))) unsigned int*)g,
        (__attribute__((address_space(3))) unsigned int*)l, 16, 0, 0);
}

// ------------------------- merged W1+W2 swizzle: fp32 [e][K][N] -> B-fragment bf16 tiles
// dst[((e*NT + nt)*KT + kt)*64 + l][j] = bf16(src[e][kt*16 + (l>>5)*8 + j][nt*32 + (l&31)])
// T1 = T2 = 589824 threads -> grid 4608x256 exactly. Block 0 zeroes cnt.
__global__ void swizzle_kernel(const float* __restrict__ W1, const float* __restrict__ W2,
                               unsigned short* __restrict__ w1s, unsigned short* __restrict__ w2s,
                               int* __restrict__ cnt) {
    if (blockIdx.x == 0 && threadIdx.x < NEXP) cnt[threadIdx.x] = 0;
    int gid = blockIdx.x * blockDim.x + threadIdx.x;
    const int T1 = NEXP * 48 * 24 * 64;        // 589824 threads for W1
    const int T2 = NEXP * 12 * 96 * 64;        // 589824 threads for W2
    const float* src; unsigned short* dst; int K, N, NT, KT, g;
    if (gid < T1)           { src = W1; dst = w1s; K = DIM; N = HID;  NT = 48; KT = 24; g = gid; }
    else if (gid < T1 + T2) { src = W2; dst = w2s; K = HID; N = OUTD; NT = 12; KT = 96; g = gid - T1; }
    else return;
    int l  = g & 63;
    int kt = (g >> 6) % KT;
    int nt = ((g >> 6) / KT) % NT;
    int e  = g / (64 * KT * NT);
    const float* s = src + ((size_t)e * K + kt * 16 + (l >> 5) * 8) * N + nt * 32 + (l & 31);
    unsigned short r[8];
    #pragma unroll
    for (int j = 0; j < 8; ++j) r[j] = f2bf(s[(size_t)j * N]);
    *(uint4*)(dst + (size_t)g * 8) = *(uint4*)r;
}

// ---------------------------------------------------------------- router
// 256 blocks x 256 thr: 32 tokens/block, 8 threads/token, coalesced 128B chunks;
// Wg staged transposed; __shfl_xor butterfly over seg bits. (R7: verified win.)
__global__ void router_kernel(const float* __restrict__ x, const float* __restrict__ Wg,
                              const float* __restrict__ bg, int* __restrict__ cnt,
                              int* __restrict__ btok, int* __restrict__ tokmap,
                              float* __restrict__ gmap) {
    __shared__ float WgL[NEXP * DIM];          // transposed: WgL[e*DIM + ch]
    __shared__ int lcnt[NEXP];
    __shared__ int lbase[NEXP];
    int tid = threadIdx.x;
    for (int i = tid; i < DIM * NEXP; i += 256) {
        int ch = i >> 3, e = i & 7;            // Wg row-major read = coalesced
        WgL[e * DIM + ch] = Wg[i];
    }
    if (tid < NEXP) lcnt[tid] = 0;
    __syncthreads();

    int tl  = tid >> 3;                        // token-in-block 0..31
    int seg = tid & 7;                         // channel segment 0..7 (lane bits 2:0)
    int t   = blockIdx.x * 32 + tl;

    float lg[NEXP] = {0.f, 0.f, 0.f, 0.f, 0.f, 0.f, 0.f, 0.f};
    const float* xr = x + (size_t)t * DIM;
    #pragma unroll
    for (int d4 = 0; d4 < 12; ++d4) {
        float4 v = *(const float4*)(xr + d4 * 32 + seg * 4);
        #pragma unroll
        for (int e = 0; e < NEXP; ++e) {
            float4 w = *(const float4*)&WgL[e * DIM + d4 * 32 + seg * 4];
            lg[e] += v.x * w.x + v.y * w.y + v.z * w.z + v.w * w.w;
        }
    }
    #pragma unroll
    for (int off = 1; off < 8; off <<= 1)
        #pragma unroll
        for (int e = 0; e < NEXP; ++e)
            lg[e] += __shfl_xor(lg[e], off);

    int p0 = 0, p1 = 0, i0 = 0, i1 = 0;
    float g0 = 0.f, g1 = 0.f;
    if (seg == 0) {
        float v0 = -INFINITY, v1 = -INFINITY;
        #pragma unroll
        for (int e = 0; e < NEXP; ++e) {
            float v = lg[e] + bg[e];
            if (v > v0)      { v1 = v0; i1 = i0; v0 = v; i0 = e; }
            else if (v > v1) { v1 = v;  i1 = e; }
        }
        float e1 = expf(v1 - v0);
        g0 = 1.f / (1.f + e1);
        g1 = e1  / (1.f + e1);
        p0 = atomicAdd(&lcnt[i0], 1);
        p1 = atomicAdd(&lcnt[i1], 1);
    }
    __syncthreads();
    if (tid < NEXP) lbase[tid] = atomicAdd(&cnt[tid], lcnt[tid]);
    __syncthreads();
    if (seg == 0) {
        int o0 = lbase[i0] + p0, o1 = lbase[i1] + p1;
        btok[i0 * N_TOK + o0] = t;
        btok[i1 * N_TOK + o1] = t;
        ((int4*)tokmap)[t] = make_int4(i0, o0, i1, o1);
        ((float2*)gmap)[t] = make_float2(g0, g1);
    }
}

// ------------------------------------------ gather x rows into A-fragment order (bf16)
__global__ void gather_kernel(const float* __restrict__ x, const int* __restrict__ cnt,
                              const int* __restrict__ btok, unsigned short* __restrict__ xg) {
    int mt = blockIdx.x, e = blockIdx.y;
    int cntE = cnt[e];
    if (mt * 32 >= cntE) return;
    int tid = threadIdx.x;                 // 256
    int m = tid & 31, kt0 = tid >> 5;      // 32 x 8
    int pos = mt * 32 + m;
    int idx = (pos < cntE) ? pos : cntE - 1;   // clamp pad rows (masked later)
    int tok = btok[e * N_TOK + idx];
    const float* xr = x + (size_t)tok * DIM;
    #pragma unroll
    for (int kk = 0; kk < 3; ++kk) {
        int kt = kt0 + kk * 8;
        #pragma unroll
        for (int kh = 0; kh < 2; ++kh) {
            float4 v0 = *(const float4*)(xr + kt * 16 + kh * 8);
            float4 v1 = *(const float4*)(xr + kt * 16 + kh * 8 + 4);
            unsigned short rr[8];
            rr[0] = f2bf(v0.x); rr[1] = f2bf(v0.y); rr[2] = f2bf(v0.z); rr[3] = f2bf(v0.w);
            rr[4] = f2bf(v1.x); rr[5] = f2bf(v1.y); rr[6] = f2bf(v1.z); rr[7] = f2bf(v1.w);
            *(uint4*)(xg + (size_t)(((e * CAP_MT + mt) * 24 + kt) * 64 + kh * 32 + m) * 8) =
                *(uint4*)rr;
        }
    }
}

// ---------------------------------------------------------------- GEMM1: h = gelu(xg@W1+b1)
// BK=96 -> 48 KB stage -> 3 blocks/CU (R10 falsified drain-count; residency is the
// operative lever per R5). 8 waves, wave-tile 64x32, acc 32 regs; launch_bounds(512,6)
// pins 6 waves/SIMD (3 blocks x 8 waves / 4 SIMD). Waves 0-3 stage A (mt=wave, 6
// kt-tiles), waves 4-7 stage B. Epilogue: bias + rcp-gelu, per-wave 64x32 transpose
// through an 80B-pitch region (conflict-free, R10-verified), store h A-fragment tiles.
__global__ __launch_bounds__(512, 6) void gemm1_kernel(
        const unsigned short* __restrict__ xg, const unsigned short* __restrict__ w1s,
        const float* __restrict__ b1, const int* __restrict__ cnt,
        unsigned short* __restrict__ h) {
    int L = blockIdx.x;                   // e in low 3 bits: XCD pin
    int e = L & 7;
    int r = L >> 3;
    int nb = r % 12;                      // 128-col slice of HID
    int tb = r / 12;                      // 128-token block
    int cntE = cnt[e];
    if (tb * 128 >= cntE) return;

    __shared__ unsigned short stg[48 * 512];   // 48 KB: A tiles [0..23], B tiles [24..47]

    int tid = threadIdx.x;
    int wave = tid >> 6, lane = tid & 63;
    int m31 = lane & 31, kh = lane >> 5;
    int wm = wave & 1;                    // 64-row half
    int wn = wave >> 1;                   // 32-col quarter (0..3)

    f32x16 acc[2];
    acc[0] = (f32x16){0.f,0.f,0.f,0.f,0.f,0.f,0.f,0.f,0.f,0.f,0.f,0.f,0.f,0.f,0.f,0.f};
    acc[1] = acc[0];

    const unsigned short* xa = xg  + ((size_t)(e * CAP_MT + tb * 4) * 24) * 512;
    const unsigned short* wb = w1s + ((size_t)(e * 48 + nb * 4) * 24) * 512;

    // hoisted per-wave staging base: waves 0-3 -> A (mt = wave), waves 4-7 -> B (nt)
    const unsigned short* sbase = (wave < 4)
        ? xa + ((size_t)wave * 24) * 512 + lane * 8
        : wb + ((size_t)(wave - 4) * 24) * 512 + lane * 8;
    unsigned short* dbase = &stg[wave * 6 * 512];

    for (int ks = 0; ks < 4; ++ks) {            // K = 384 = 4 x BK96
        __syncthreads();                         // stg free
        const unsigned short* sk = sbase + ks * 3072;   // 6 kt-tiles per ks
        #pragma unroll
        for (int q = 0; q < 6; ++q)
            cp16(sk + q * 512, dbase + q * 512);
        __syncthreads();                         // drain: tiles visible
        #pragma unroll
        for (int kt = 0; kt < 6; ++kt) {
            bf16x8 b  = *(const bf16x8*)&stg[(24 + wn * 6 + kt) * 512 + lane * 8];
            bf16x8 a0 = *(const bf16x8*)&stg[((wm * 2 + 0) * 6 + kt) * 512 + lane * 8];
            bf16x8 a1 = *(const bf16x8*)&stg[((wm * 2 + 1) * 6 + kt) * 512 + lane * 8];
            acc[0] = __builtin_amdgcn_mfma_f32_32x32x16_bf16(a0, b, acc[0], 0, 0, 0);
            acc[1] = __builtin_amdgcn_mfma_f32_32x32x16_bf16(a1, b, acc[1], 0, 0, 0);
        }
    }

    // ---- epilogue: bias + gelu -> per-wave 5 KB region (80B pitch), then h tiles ----
    __syncthreads();                             // all waves done reading stg
    char* hw = (char*)stg + wave * 5120;         // 64 rows x 80 B (40 KB total <= 48 KB)
    float bv = b1[e * HID + nb * 128 + wn * 32 + m31];
    #pragma unroll
    for (int s = 0; s < 2; ++s)
        #pragma unroll
        for (int rr = 0; rr < 16; ++rr) {
            int rowl = s * 32 + (rr & 3) + 8 * (rr >> 2) + 4 * kh;   // 0..63 (token row)
            *(unsigned short*)(hw + rowl * 80 + m31 * 2) = f2bf(gelu_fast(acc[s][rr] + bv));
        }
    // read back as A-fragment tiles (lane l: row = l&31, k = (l>>5)*8 + j), store h.
    // wave-private region: compiler inserts the lgkmcnt for the RAW.
    #pragma unroll
    for (int mtl = 0; mtl < 2; ++mtl)
        #pragma unroll
        for (int ktl = 0; ktl < 2; ++ktl) {
            uint4 v = *(const uint4*)(hw + (mtl * 32 + m31) * 80 + (ktl * 16 + kh * 8) * 2);
            int mt = tb * 4 + wm * 2 + mtl;           // token tile (32 rows)
            int kt = nb * 8 + wn * 2 + ktl;           // hid tile (16 k)
            *(uint4*)(h + ((size_t)((e * CAP_MT + mt) * 96 + kt)) * 512 + lane * 8) = v;
        }
}

// ---------------------------------------------------------------- GEMM2: yp = h @ W2
// Tile 64x128 -> 864 blocks (vs 432): the old grid capped residency at ~1.7 blocks/CU
// (grid-limited, not LDS-limited). 48 KB stage -> 3 blocks/CU resident. 8 waves,
// wave-tile 32x32 (acc 16 regs), BK=128 (12 rounds). Full-K f32 accumulation;
// epilogue transposes 32x32 per wave via a 2 KB region.
__global__ __launch_bounds__(512, 6) void gemm2_kernel(
        const unsigned short* __restrict__ h, const unsigned short* __restrict__ w2s,
        const int* __restrict__ cnt, unsigned short* __restrict__ yp) {
    int L = blockIdx.x;
    int e = L & 7;
    int r = L >> 3;
    int nb = r % 3;                        // 128-col slice of OUTD
    int tb = r / 3;                        // 64-token block (0..35)
    int cntE = cnt[e];
    if (tb * 64 >= cntE) return;

    __shared__ unsigned short stg[48 * 512];   // 48 KB: A tiles [0..15], B tiles [16..47]

    int tid = threadIdx.x;
    int wave = tid >> 6, lane = tid & 63;
    int m31 = lane & 31, kh = lane >> 5;
    int wm = wave & 1;                     // 32-row half
    int wn = wave >> 1;                    // 32-col quarter (0..3)

    f32x16 acc;
    acc = (f32x16){0.f,0.f,0.f,0.f,0.f,0.f,0.f,0.f,0.f,0.f,0.f,0.f,0.f,0.f,0.f,0.f};

    const unsigned short* xa = h   + ((size_t)(e * CAP_MT + tb * 2) * 96) * 512;
    const unsigned short* wb = w2s + ((size_t)(e * 12 + nb * 4) * 96) * 512;

    for (int ks = 0; ks < 12; ++ks) {          // K = 1536 = 12 x BK128
        __syncthreads();
        #pragma unroll
        for (int q = 0; q < 6; ++q) {           // 48 tiles, 6 cp16/wave
            int tl = wave * 6 + q;
            const unsigned short* src = (tl < 16)
                ? xa + ((size_t)((tl >> 3) * 96 + ks * 8 + (tl & 7))) * 512
                : wb + ((size_t)(((tl - 16) >> 3) * 96 + ks * 8 + ((tl - 16) & 7))) * 512;
            cp16(src + lane * 8, &stg[tl * 512]);
        }
        __syncthreads();
        #pragma unroll
        for (int kt = 0; kt < 8; ++kt) {
            bf16x8 a = *(const bf16x8*)&stg[(wm * 8 + kt) * 512 + lane * 8];
            bf16x8 b = *(const bf16x8*)&stg[(16 + wn * 8 + kt) * 512 + lane * 8];
            acc = __builtin_amdgcn_mfma_f32_32x32x16_bf16(a, b, acc, 0, 0, 0);
        }
    }

    // ---- epilogue: per-wave 2 KB region (32 rows x 64 B), rows [wm*32..+32) x cols
    //      [wn*32..+32) of the 64x128 tile ----
    __syncthreads();                           // all waves done with stage reads
    char* hw = (char*)stg + wave * 2048;       // 32 rows x 64 B = 2048 B per wave
    #pragma unroll
    for (int rr = 0; rr < 16; ++rr) {
        int rowl = (rr & 3) + 8 * (rr >> 2) + 4 * kh;   // 0..31
        *(unsigned short*)(hw + rowl * 64 + m31 * 2) = f2bf(acc[rr]);
    }
    // read-back: 2 passes, addr = rowl*64 + cc*16 (4-way max); store row-major
    #pragma unroll
    for (int it = 0; it < 2; ++it) {
        int rowl = it * 16 + (lane >> 2);
        int cc   = lane & 3;
        uint4 v = *(const uint4*)(hw + rowl * 64 + cc * 16);
        int pos = tb * 64 + wm * 32 + rowl;
        *(uint4*)(yp + (size_t)(e * CAP_TOK + pos) * OUTD + nb * 128 + wn * 32 + cc * 8) = v;
    }
}

// ----------- reduce: out = sum_k g_k * (yp[e_k][pos_k] + b2[e_k]); single full-K partial
__global__ void reduce_kernel(const unsigned short* __restrict__ yp,
                              const int* __restrict__ tokmap, const float* __restrict__ gmap,
                              const float* __restrict__ b2, float* __restrict__ out) {
    int gid = blockIdx.x * 256 + threadIdx.x;      // N_TOK * 48 threads
    int t = gid / 48, q = gid - t * 48;            // q: 8-col group
    int4   tm = ((const int4*)tokmap)[t];
    float2 g  = ((const float2*)gmap)[t];
    const unsigned short* p0 = yp + ((size_t)(tm.x * CAP_TOK + tm.y)) * OUTD + q * 8;
    const unsigned short* p1 = yp + ((size_t)(tm.z * CAP_TOK + tm.w)) * OUTD + q * 8;
    u16x8 a = __builtin_nontemporal_load((const u16x8*)p0);
    u16x8 b = __builtin_nontemporal_load((const u16x8*)p1);
    const float* c0 = &b2[tm.x * OUTD + q * 8];
    const float* c1 = &b2[tm.z * OUTD + q * 8];
    f32x4 r0, r1;
    #pragma unroll
    for (int j = 0; j < 4; ++j) {
        r0[j] = g.x * (bf2f(a[j]) + c0[j]) + g.y * (bf2f(b[j]) + c1[j]);
        r1[j] = g.x * (bf2f(a[4 + j]) + c0[4 + j]) + g.y * (bf2f(b[4 + j]) + c1[4 + j]);
    }
    float* op = &out[(size_t)t * OUTD + q * 8];
    __builtin_nontemporal_store(r0, (f32x4*)op);
    __builtin_nontemporal_store(r1, (f32x4*)(op + 4));
}

// ---------------------------------------------------------------- launch
extern "C" void kernel_launch(void* const* d_in, const int* in_sizes, int n_in,
                              void* d_out, int out_size, void* d_ws, size_t ws_size,
                              hipStream_t stream) {
    const float* x  = (const float*)d_in[0];
    const float* Wg = (const float*)d_in[1];
    const float* bg = (const float*)d_in[2];
    const float* W1 = (const float*)d_in[3];
    const float* b1 = (const float*)d_in[4];
    const float* W2 = (const float*)d_in[5];
    const float* b2 = (const float*)d_in[6];
    float* out = (float*)d_out;

    char* ws = (char*)d_ws;                                    // all offsets 1KB-aligned
    int*            cnt    = (int*)ws;                         // 32 B
    int*            btok   = (int*)(ws + 1024);                // 256 KB
    int*            tokmap = (int*)(ws + 263168);              // 128 KB
    float*          gmap   = (float*)(ws + 394240);            // 64 KB
    unsigned short* xg     = (unsigned short*)(ws + 459776);   // 13.5 MB (tiles 8x72x24)
    unsigned short* w1s    = (unsigned short*)(ws + 14615552); // 9.44 MB
    unsigned short* w2s    = (unsigned short*)(ws + 24052736); // 9.44 MB
    unsigned short* h      = (unsigned short*)(ws + 33489920); // 56.6 MB (tiles 8x72x96)
    // yp (8 x 2304 x 384 bf16 = 13.5 MB) aliases the xg slot: gemm2 runs strictly after
    // gemm1's last read of xg (same stream), and next iteration's gather fully rewrites
    // the tiles gemm1 reads. Keeps workspace footprint identical.
    unsigned short* yp     = xg;

    // merged W1+W2 swizzle: (589824 + 589824) / 256 = 4608 blocks exactly
    hipLaunchKernelGGL(swizzle_kernel, dim3(4608), dim3(256), 0, stream,
                       W1, W2, w1s, w2s, cnt);
    hipLaunchKernelGGL(router_kernel, dim3(N_TOK / 32), dim3(256), 0, stream,
                       x, Wg, bg, cnt, btok, tokmap, gmap);
    hipLaunchKernelGGL(gather_kernel, dim3(CAP_MT, NEXP), dim3(256), 0, stream,
                       x, cnt, btok, xg);
    hipLaunchKernelGGL(gemm1_kernel, dim3(NEXP * 12 * CAP_TB), dim3(512), 0, stream,
                       xg, w1s, b1, cnt, h);
    hipLaunchKernelGGL(gemm2_kernel, dim3(NEXP * 3 * CAP_TB2), dim3(512), 0, stream,
                       h, w2s, cnt, yp);
    hipLaunchKernelGGL(reduce_kernel, dim3(N_TOK * 48 / 256), dim3(256), 0, stream,
                       yp, tokmap, gmap, b2, out);
}

// Round 12
// 183.153 us; speedup vs baseline: 1.0572x; 1.0572x over previous
//
#include <hip/hip_runtime.h>
#include <cmath>

#define N_TOK 8192
#define DIM   384
#define NEXP  8
#define HID   1536
#define OUTD  384
#define CAP_MT 72        // 32-row gather tiles per expert (2304 tokens, mean 2048 + 6 sigma)
#define CAP_TOK 2304
#define CAP_TB 18        // 128-row blocks per expert

typedef __attribute__((ext_vector_type(8)))  __bf16 bf16x8;
typedef __attribute__((ext_vector_type(16))) float  f32x16;
typedef __attribute__((ext_vector_type(4)))  float  f32x4;          // nontemporal builtins
typedef __attribute__((ext_vector_type(8)))  unsigned short u16x8;  // nontemporal bf16 loads

__device__ __forceinline__ unsigned short f2bf(float f) {
    unsigned u = __float_as_uint(f);
    u += 0x7FFF + ((u >> 16) & 1);          // round-to-nearest-even
    return (unsigned short)(u >> 16);
}

__device__ __forceinline__ float bf2f(unsigned short s) {
    return __uint_as_float(((unsigned)s) << 16);
}

// R7 lesson: A&S-polynomial gelu with a (non-fast-math) IEEE divide + __expf is SLOWER
// than libm erff (VALUBusy 43->56%). Held at erff since R8 (one-lever discipline).
__device__ __forceinline__ float gelu_exact(float x) {
    return 0.5f * x * (1.0f + erff(x * 0.70710678118654752f));
}

// async global->LDS, 16B per lane; LDS dest = wave-uniform tile base (HW adds lane*16)
__device__ __forceinline__ void cp16(const unsigned short* g, unsigned short* l) {
    __builtin_amdgcn_global_load_lds(
        (const __attribute__((address_space(1))) unsigned int*)g,
        (__attribute__((address_space(3))) unsigned int*)l, 16, 0, 0);
}

// ------------------------- merged W1+W2 swizzle: fp32 [e][K][N] -> B-fragment bf16 tiles
// dst[((e*NT + nt)*KT + kt)*64 + l][j] = bf16(src[e][kt*16 + (l>>5)*8 + j][nt*32 + (l&31)])
// T1 = T2 = 589824 threads -> grid 4608x256 exactly. Block 0 zeroes cnt.
__global__ void swizzle_kernel(const float* __restrict__ W1, const float* __restrict__ W2,
                               unsigned short* __restrict__ w1s, unsigned short* __restrict__ w2s,
                               int* __restrict__ cnt) {
    if (blockIdx.x == 0 && threadIdx.x < NEXP) cnt[threadIdx.x] = 0;
    int gid = blockIdx.x * blockDim.x + threadIdx.x;
    const int T1 = NEXP * 48 * 24 * 64;        // 589824 threads for W1
    const int T2 = NEXP * 12 * 96 * 64;        // 589824 threads for W2
    const float* src; unsigned short* dst; int K, N, NT, KT, g;
    if (gid < T1)           { src = W1; dst = w1s; K = DIM; N = HID;  NT = 48; KT = 24; g = gid; }
    else if (gid < T1 + T2) { src = W2; dst = w2s; K = HID; N = OUTD; NT = 12; KT = 96; g = gid - T1; }
    else return;
    int l  = g & 63;
    int kt = (g >> 6) % KT;
    int nt = ((g >> 6) / KT) % NT;
    int e  = g / (64 * KT * NT);
    const float* s = src + ((size_t)e * K + kt * 16 + (l >> 5) * 8) * N + nt * 32 + (l & 31);
    unsigned short r[8];
    #pragma unroll
    for (int j = 0; j < 8; ++j) r[j] = f2bf(s[(size_t)j * N]);
    *(uint4*)(dst + (size_t)g * 8) = *(uint4*)r;
}

// ---------------------------------------------------------------- router
// 256 blocks x 256 thr: 32 tokens/block, 8 threads/token, coalesced 128B chunks;
// Wg staged transposed; __shfl_xor butterfly over seg bits. (R7: verified win.)
__global__ void router_kernel(const float* __restrict__ x, const float* __restrict__ Wg,
                              const float* __restrict__ bg, int* __restrict__ cnt,
                              int* __restrict__ btok, int* __restrict__ tokmap,
                              float* __restrict__ gmap) {
    __shared__ float WgL[NEXP * DIM];          // transposed: WgL[e*DIM + ch]
    __shared__ int lcnt[NEXP];
    __shared__ int lbase[NEXP];
    int tid = threadIdx.x;
    for (int i = tid; i < DIM * NEXP; i += 256) {
        int ch = i >> 3, e = i & 7;            // Wg row-major read = coalesced
        WgL[e * DIM + ch] = Wg[i];
    }
    if (tid < NEXP) lcnt[tid] = 0;
    __syncthreads();

    int tl  = tid >> 3;                        // token-in-block 0..31
    int seg = tid & 7;                         // channel segment 0..7 (lane bits 2:0)
    int t   = blockIdx.x * 32 + tl;

    float lg[NEXP] = {0.f, 0.f, 0.f, 0.f, 0.f, 0.f, 0.f, 0.f};
    const float* xr = x + (size_t)t * DIM;
    #pragma unroll
    for (int d4 = 0; d4 < 12; ++d4) {
        float4 v = *(const float4*)(xr + d4 * 32 + seg * 4);
        #pragma unroll
        for (int e = 0; e < NEXP; ++e) {
            float4 w = *(const float4*)&WgL[e * DIM + d4 * 32 + seg * 4];
            lg[e] += v.x * w.x + v.y * w.y + v.z * w.z + v.w * w.w;
        }
    }
    #pragma unroll
    for (int off = 1; off < 8; off <<= 1)
        #pragma unroll
        for (int e = 0; e < NEXP; ++e)
            lg[e] += __shfl_xor(lg[e], off);

    int p0 = 0, p1 = 0, i0 = 0, i1 = 0;
    float g0 = 0.f, g1 = 0.f;
    if (seg == 0) {
        float v0 = -INFINITY, v1 = -INFINITY;
        #pragma unroll
        for (int e = 0; e < NEXP; ++e) {
            float v = lg[e] + bg[e];
            if (v > v0)      { v1 = v0; i1 = i0; v0 = v; i0 = e; }
            else if (v > v1) { v1 = v;  i1 = e; }
        }
        float e1 = expf(v1 - v0);
        g0 = 1.f / (1.f + e1);
        g1 = e1  / (1.f + e1);
        p0 = atomicAdd(&lcnt[i0], 1);
        p1 = atomicAdd(&lcnt[i1], 1);
    }
    __syncthreads();
    if (tid < NEXP) lbase[tid] = atomicAdd(&cnt[tid], lcnt[tid]);
    __syncthreads();
    if (seg == 0) {
        int o0 = lbase[i0] + p0, o1 = lbase[i1] + p1;
        btok[i0 * N_TOK + o0] = t;
        btok[i1 * N_TOK + o1] = t;
        ((int4*)tokmap)[t] = make_int4(i0, o0, i1, o1);
        ((float2*)gmap)[t] = make_float2(g0, g1);
    }
}

// ------------------------------------------ gather x rows into A-fragment order (bf16)
__global__ void gather_kernel(const float* __restrict__ x, const int* __restrict__ cnt,
                              const int* __restrict__ btok, unsigned short* __restrict__ xg) {
    int mt = blockIdx.x, e = blockIdx.y;
    int cntE = cnt[e];
    if (mt * 32 >= cntE) return;
    int tid = threadIdx.x;                 // 256
    int m = tid & 31, kt0 = tid >> 5;      // 32 x 8
    int pos = mt * 32 + m;
    int idx = (pos < cntE) ? pos : cntE - 1;   // clamp pad rows (masked later)
    int tok = btok[e * N_TOK + idx];
    const float* xr = x + (size_t)tok * DIM;
    #pragma unroll
    for (int kk = 0; kk < 3; ++kk) {
        int kt = kt0 + kk * 8;
        #pragma unroll
        for (int kh = 0; kh < 2; ++kh) {
            float4 v0 = *(const float4*)(xr + kt * 16 + kh * 8);
            float4 v1 = *(const float4*)(xr + kt * 16 + kh * 8 + 4);
            unsigned short rr[8];
            rr[0] = f2bf(v0.x); rr[1] = f2bf(v0.y); rr[2] = f2bf(v0.z); rr[3] = f2bf(v0.w);
            rr[4] = f2bf(v1.x); rr[5] = f2bf(v1.y); rr[6] = f2bf(v1.z); rr[7] = f2bf(v1.w);
            *(uint4*)(xg + (size_t)(((e * CAP_MT + mt) * 24 + kt) * 64 + kh * 32 + m) * 8) =
                *(uint4*)rr;
        }
    }
}

// ---------------------------------------------------------------- GEMM1: h = gelu(xg@W1+b1)
// T3 minimum-2-phase double buffer (the one structural lever not yet tried unfused):
// issue round ks+1 into buf[(ks+1)&1] BEFORE consuming buf[ks&1], ONE barrier per
// round. The L2->LDS round-trip of round ks+1 flies under consume(ks) — vs the old
// issue->drain->consume where it was fully exposed (m233 2-phase stall). Barrier
// count 12 -> 7. R10/R11 falsified drain-count and residency; this targets the
// latency exposure itself. BK=64, 2x32KB buffers, 8 waves, wave-tile 64x32.
__global__ __launch_bounds__(512, 4) void gemm1_kernel(
        const unsigned short* __restrict__ xg, const unsigned short* __restrict__ w1s,
        const float* __restrict__ b1, const int* __restrict__ cnt,
        unsigned short* __restrict__ h) {
    int L = blockIdx.x;                   // e in low 3 bits: XCD pin
    int e = L & 7;
    int r = L >> 3;
    int nb = r % 12;                      // 128-col slice of HID
    int tb = r / 12;                      // 128-token block
    int cntE = cnt[e];
    if (tb * 128 >= cntE) return;

    __shared__ unsigned short stg[2][16384];   // 2 x 32 KB; per buf: A [0..15], B [16..31]

    int tid = threadIdx.x;
    int wave = tid >> 6, lane = tid & 63;
    int m31 = lane & 31, kh = lane >> 5;
    int wm = wave & 1;                    // 64-row half
    int wn = wave >> 1;                   // 32-col quarter (0..3)

    f32x16 acc[2];
    acc[0] = (f32x16){0.f,0.f,0.f,0.f,0.f,0.f,0.f,0.f,0.f,0.f,0.f,0.f,0.f,0.f,0.f,0.f};
    acc[1] = acc[0];

    const unsigned short* xa = xg  + ((size_t)(e * CAP_MT + tb * 4) * 24) * 512;
    const unsigned short* wb = w1s + ((size_t)(e * 48 + nb * 4) * 24) * 512;

    // per-wave staging source base: waves 0-3 -> A (mt = wave), waves 4-7 -> B (nt).
    // Per round: 4 contiguous kt-tiles starting at ks*4.
    const unsigned short* sbase = (wave < 4)
        ? xa + ((size_t)wave * 24) * 512 + lane * 8
        : wb + ((size_t)(wave - 4) * 24) * 512 + lane * 8;
    int tbase = (wave < 4) ? wave * 4 : 16 + (wave - 4) * 4;   // tile slot in buf

    auto issue = [&](int ks) {
        unsigned short* dst = &stg[ks & 1][tbase * 512];
        const unsigned short* sk = sbase + (size_t)ks * 2048;  // 4 tiles x 512 shorts
        #pragma unroll
        for (int q = 0; q < 4; ++q)
            cp16(sk + q * 512, dst + q * 512);
    };

    issue(0);
    for (int ks = 0; ks < 6; ++ks) {            // K = 384 = 6 x BK64
        __syncthreads();                         // buf[ks&1] landed (implicit vmcnt(0)
                                                 // drain) + prev consume complete
        if (ks < 5) issue(ks + 1);               // prefetch flies under consume below
        const unsigned short* bufp = stg[ks & 1];
        #pragma unroll
        for (int kt = 0; kt < 4; ++kt) {
            bf16x8 b  = *(const bf16x8*)&bufp[(16 + wn * 4 + kt) * 512 + lane * 8];
            bf16x8 a0 = *(const bf16x8*)&bufp[((wm * 2 + 0) * 4 + kt) * 512 + lane * 8];
            bf16x8 a1 = *(const bf16x8*)&bufp[((wm * 2 + 1) * 4 + kt) * 512 + lane * 8];
            acc[0] = __builtin_amdgcn_mfma_f32_32x32x16_bf16(a0, b, acc[0], 0, 0, 0);
            acc[1] = __builtin_amdgcn_mfma_f32_32x32x16_bf16(a1, b, acc[1], 0, 0, 0);
        }
    }

    // ---- epilogue: bias + gelu -> per-wave 5 KB region (80B pitch), then h tiles ----
    __syncthreads();                             // all waves done reading stg
    char* hw = (char*)stg + wave * 5120;         // 64 rows x 80 B (40 KB <= 64 KB)
    float bv = b1[e * HID + nb * 128 + wn * 32 + m31];
    #pragma unroll
    for (int s = 0; s < 2; ++s)
        #pragma unroll
        for (int rr = 0; rr < 16; ++rr) {
            int rowl = s * 32 + (rr & 3) + 8 * (rr >> 2) + 4 * kh;   // 0..63 (token row)
            *(unsigned short*)(hw + rowl * 80 + m31 * 2) = f2bf(gelu_exact(acc[s][rr] + bv));
        }
    // read back as A-fragment tiles (lane l: row = l&31, k = (l>>5)*8 + j), store h.
    // wave-private region: compiler inserts the lgkmcnt for the RAW.
    #pragma unroll
    for (int mtl = 0; mtl < 2; ++mtl)
        #pragma unroll
        for (int ktl = 0; ktl < 2; ++ktl) {
            uint4 v = *(const uint4*)(hw + (mtl * 32 + m31) * 80 + (ktl * 16 + kh * 8) * 2);
            int mt = tb * 4 + wm * 2 + mtl;           // token tile (32 rows)
            int kt = nb * 8 + wn * 2 + ktl;           // hid tile (16 k)
            *(uint4*)(h + ((size_t)((e * CAP_MT + mt) * 96 + kt)) * 512 + lane * 8) = v;
        }
}

// ---------------------------------------------------------------- GEMM2: yp = h @ W2
// R10 form restored (R11's 64x128 retile doubled W2 staged bytes -> regression).
// BK=128, 128x128 tile, 8 waves, wave-tile 64x32, 64 KB stage, hoisted bases.
// Full-K f32 accumulation; epilogue transposes 64x32 per wave via 4 KB region.
__global__ __launch_bounds__(512, 4) void gemm2_kernel(
        const unsigned short* __restrict__ h, const unsigned short* __restrict__ w2s,
        const int* __restrict__ cnt, unsigned short* __restrict__ yp) {
    int L = blockIdx.x;
    int e = L & 7;
    int r = L >> 3;
    int nb = r % 3;                        // 128-col slice of OUTD
    int tb = r / 3;                        // 128-token block
    int cntE = cnt[e];
    if (tb * 128 >= cntE) return;

    __shared__ unsigned short stg[64 * 512];   // 64 KB: A tiles [0..31], B tiles [32..63]

    int tid = threadIdx.x;
    int wave = tid >> 6, lane = tid & 63;
    int m31 = lane & 31, kh = lane >> 5;
    int wm = wave & 1;                     // 64-row half
    int wn = wave >> 1;                    // 32-col quarter (0..3)

    f32x16 acc[2];
    acc[0] = (f32x16){0.f,0.f,0.f,0.f,0.f,0.f,0.f,0.f,0.f,0.f,0.f,0.f,0.f,0.f,0.f,0.f};
    acc[1] = acc[0];

    const unsigned short* xa = h   + ((size_t)(e * CAP_MT + tb * 4) * 96) * 512;
    const unsigned short* wb = w2s + ((size_t)(e * 12 + nb * 4) * 96) * 512;

    const unsigned short* sbase = (wave < 4)
        ? xa + ((size_t)wave * 96) * 512 + lane * 8
        : wb + ((size_t)(wave - 4) * 96) * 512 + lane * 8;
    unsigned short* dbase = &stg[wave * 8 * 512];

    for (int ks = 0; ks < 12; ++ks) {          // K = 1536 = 12 x BK128
        __syncthreads();
        const unsigned short* sk = sbase + ks * 4096;
        #pragma unroll
        for (int q = 0; q < 8; ++q)
            cp16(sk + q * 512, dbase + q * 512);
        __syncthreads();
        #pragma unroll
        for (int kt = 0; kt < 8; ++kt) {
            bf16x8 b  = *(const bf16x8*)&stg[(32 + wn * 8 + kt) * 512 + lane * 8];
            bf16x8 a0 = *(const bf16x8*)&stg[((wm * 2 + 0) * 8 + kt) * 512 + lane * 8];
            bf16x8 a1 = *(const bf16x8*)&stg[((wm * 2 + 1) * 8 + kt) * 512 + lane * 8];
            acc[0] = __builtin_amdgcn_mfma_f32_32x32x16_bf16(a0, b, acc[0], 0, 0, 0);
            acc[1] = __builtin_amdgcn_mfma_f32_32x32x16_bf16(a1, b, acc[1], 0, 0, 0);
        }
    }

    // ---- epilogue: per-wave 4 KB region (64 rows x 64 B) ----
    __syncthreads();                           // all waves done with stage reads
    char* hw = (char*)stg + wave * 4096;       // 64 rows x 64 B = 4096 B per wave
    #pragma unroll
    for (int s = 0; s < 2; ++s)
        #pragma unroll
        for (int rr = 0; rr < 16; ++rr) {
            int rowl = s * 32 + (rr & 3) + 8 * (rr >> 2) + 4 * kh;   // 0..63
            *(unsigned short*)(hw + rowl * 64 + m31 * 2) = f2bf(acc[s][rr]);
        }
    // read-back: addr = it*1024 + lane*16 (4-way max); store row-major
    #pragma unroll
    for (int it = 0; it < 4; ++it) {
        int rowl = it * 16 + (lane >> 2);
        int cc   = lane & 3;
        uint4 v = *(const uint4*)(hw + rowl * 64 + cc * 16);
        int pos = tb * 128 + wm * 64 + rowl;
        *(uint4*)(yp + (size_t)(e * CAP_TOK + pos) * OUTD + nb * 128 + wn * 32 + cc * 8) = v;
    }
}

// ----------- reduce: out = sum_k g_k * (yp[e_k][pos_k] + b2[e_k]); single full-K partial
__global__ void reduce_kernel(const unsigned short* __restrict__ yp,
                              const int* __restrict__ tokmap, const float* __restrict__ gmap,
                              const float* __restrict__ b2, float* __restrict__ out) {
    int gid = blockIdx.x * 256 + threadIdx.x;      // N_TOK * 48 threads
    int t = gid / 48, q = gid - t * 48;            // q: 8-col group
    int4   tm = ((const int4*)tokmap)[t];
    float2 g  = ((const float2*)gmap)[t];
    const unsigned short* p0 = yp + ((size_t)(tm.x * CAP_TOK + tm.y)) * OUTD + q * 8;
    const unsigned short* p1 = yp + ((size_t)(tm.z * CAP_TOK + tm.w)) * OUTD + q * 8;
    u16x8 a = __builtin_nontemporal_load((const u16x8*)p0);
    u16x8 b = __builtin_nontemporal_load((const u16x8*)p1);
    const float* c0 = &b2[tm.x * OUTD + q * 8];
    const float* c1 = &b2[tm.z * OUTD + q * 8];
    f32x4 r0, r1;
    #pragma unroll
    for (int j = 0; j < 4; ++j) {
        r0[j] = g.x * (bf2f(a[j]) + c0[j]) + g.y * (bf2f(b[j]) + c1[j]);
        r1[j] = g.x * (bf2f(a[4 + j]) + c0[4 + j]) + g.y * (bf2f(b[4 + j]) + c1[4 + j]);
    }
    float* op = &out[(size_t)t * OUTD + q * 8];
    __builtin_nontemporal_store(r0, (f32x4*)op);
    __builtin_nontemporal_store(r1, (f32x4*)(op + 4));
}

// ---------------------------------------------------------------- launch
extern "C" void kernel_launch(void* const* d_in, const int* in_sizes, int n_in,
                              void* d_out, int out_size, void* d_ws, size_t ws_size,
                              hipStream_t stream) {
    const float* x  = (const float*)d_in[0];
    const float* Wg = (const float*)d_in[1];
    const float* bg = (const float*)d_in[2];
    const float* W1 = (const float*)d_in[3];
    const float* b1 = (const float*)d_in[4];
    const float* W2 = (const float*)d_in[5];
    const float* b2 = (const float*)d_in[6];
    float* out = (float*)d_out;

    char* ws = (char*)d_ws;                                    // all offsets 1KB-aligned
    int*            cnt    = (int*)ws;                         // 32 B
    int*            btok   = (int*)(ws + 1024);                // 256 KB
    int*            tokmap = (int*)(ws + 263168);              // 128 KB
    float*          gmap   = (float*)(ws + 394240);            // 64 KB
    unsigned short* xg     = (unsigned short*)(ws + 459776);   // 13.5 MB (tiles 8x72x24)
    unsigned short* w1s    = (unsigned short*)(ws + 14615552); // 9.44 MB
    unsigned short* w2s    = (unsigned short*)(ws + 24052736); // 9.44 MB
    unsigned short* h      = (unsigned short*)(ws + 33489920); // 56.6 MB (tiles 8x72x96)
    // yp (8 x 2304 x 384 bf16 = 13.5 MB) aliases the xg slot: gemm2 runs strictly after
    // gemm1's last read of xg (same stream), and next iteration's gather fully rewrites
    // the tiles gemm1 reads. Keeps workspace footprint identical.
    unsigned short* yp     = xg;

    // merged W1+W2 swizzle: (589824 + 589824) / 256 = 4608 blocks exactly
    hipLaunchKernelGGL(swizzle_kernel, dim3(4608), dim3(256), 0, stream,
                       W1, W2, w1s, w2s, cnt);
    hipLaunchKernelGGL(router_kernel, dim3(N_TOK / 32), dim3(256), 0, stream,
                       x, Wg, bg, cnt, btok, tokmap, gmap);
    hipLaunchKernelGGL(gather_kernel, dim3(CAP_MT, NEXP), dim3(256), 0, stream,
                       x, cnt, btok, xg);
    hipLaunchKernelGGL(gemm1_kernel, dim3(NEXP * 12 * CAP_TB), dim3(512), 0, stream,
                       xg, w1s, b1, cnt, h);
    hipLaunchKernelGGL(gemm2_kernel, dim3(NEXP * 3 * CAP_TB), dim3(512), 0, stream,
                       h, w2s, cnt, yp);
    hipLaunchKernelGGL(reduce_kernel, dim3(N_TOK * 48 / 256), dim3(256), 0, stream,
                       yp, tokmap, gmap, b2, out);
}